// Round 8
// baseline (63.910 us; speedup 1.0000x reference)
//
#include <hip/hip_runtime.h>
#include <math.h>

#define N_I 1152
#define N_O 10
#define N_D 16
#define BLK 256
#define KPT 18            // i-rows per thread: 1152 / (BLK/4)
#define ROWS (N_O * N_D)  // 160 floats per i-row
#define NITEM 5           // o's per block: one half-b

// Persistent, perfectly balanced: grid = B*2 = 512 blocks = exactly 2/CU,
// each block routes the 5 consecutive o's of one half-b. Single register
// tile u[18] (72 data VGPRs); after r2's k-loop consumes u[] for the last
// time, the NEXT item's 18 loads refill it in place (round-6 proven: no
// remat, VGPR~100), so VMEM requests stay in flight through r2-reduce and
// the next item's r0. No generation boundaries, no imbalance. Consecutive
// o's give deterministic in-block L2 reuse of the shared 128B lines.
template<bool PRE>
__device__ __forceinline__ void route_item(
    float4 (&u)[KPT], const float* __restrict__ gnext,
    float* __restrict__ outp,
    int tid, int wave, int lane, int d4,
    float (*scr_s)[16], float* scr_e, float* vcum)
{
    if (tid < 16) vcum[tid] = 0.0f;   // safe: barrier at end of prev item
    float4 vc = make_float4(0.f, 0.f, 0.f, 0.f);
    #pragma unroll
    for (int r = 0; r < 3; ++r) {
        float4 s4 = make_float4(0.f, 0.f, 0.f, 0.f);
        float esum;
        if (r == 0) {
            #pragma unroll
            for (int k = 0; k < KPT; ++k) {   // compiler staggers vmcnt here
                s4.x += u[k].x; s4.y += u[k].y;
                s4.z += u[k].z; s4.w += u[k].w;
            }
            esum = (float)KPT;    // b == 0 -> uniform weights, e_i = 1
        } else {
            esum = 0.0f;
            #pragma unroll
            for (int k = 0; k < KPT; ++k) {
                float p = u[k].x*vc.x + u[k].y*vc.y + u[k].z*vc.z + u[k].w*vc.w;
                p += __shfl_xor(p, 1);    // quad butterfly: full 16-dim dot
                p += __shfl_xor(p, 2);
                const float e = __expf(p);
                esum += e;
                s4.x += e*u[k].x; s4.y += e*u[k].y;
                s4.z += e*u[k].z; s4.w += e*u[k].w;
            }
        }
        if (PRE && r == 2) {
            // u[] is dead after r2's k-loop: refill with the next item.
            __builtin_amdgcn_sched_barrier(0);   // don't hoist above r2 compute
            #pragma unroll
            for (int k = 0; k < KPT; ++k)
                u[k] = *(const float4*)(gnext + (size_t)(k << 6) * ROWS);
            __builtin_amdgcn_sched_barrier(0);   // don't sink below
        }
        // reduce over ig within the wave (lane bits 2..5)
        #pragma unroll
        for (int m = 4; m <= 32; m <<= 1) {
            s4.x += __shfl_xor(s4.x, m);
            s4.y += __shfl_xor(s4.y, m);
            s4.z += __shfl_xor(s4.z, m);
            s4.w += __shfl_xor(s4.w, m);
            esum += __shfl_xor(esum, m);
        }
        if (lane < 4) {
            scr_s[wave][lane*4+0] = s4.x;
            scr_s[wave][lane*4+1] = s4.y;
            scr_s[wave][lane*4+2] = s4.z;
            scr_s[wave][lane*4+3] = s4.w;
            if (lane == 0) scr_e[wave] = esum;
        }
        __syncthreads();
        if (tid < 16) {
            float s = 0.f, et = 0.f;
            #pragma unroll
            for (int w = 0; w < 4; ++w) { s += scr_s[w][tid]; et += scr_e[w]; }
            s /= et;                           // softmax normalization folded
            float sq = s * s;
            sq += __shfl_xor(sq, 1);
            sq += __shfl_xor(sq, 2);
            sq += __shfl_xor(sq, 4);
            sq += __shfl_xor(sq, 8);
            const float nrm = sqrtf(sq);
            const float v = s * (nrm / (1.0f + sq));   // == sq*s/((1+sq)*nrm)
            if (r == 2) outp[tid] = v;
            else        vcum[tid] += v;        // logit state: b_i = u_i . vcum
        }
        __syncthreads();
        if (r < 2) vc = ((const float4*)vcum)[d4];
    }
}

__global__ __launch_bounds__(BLK, 2)
void caps_route(const float* __restrict__ u_hat, float* __restrict__ out)
{
    __shared__ float scr_s[4][16];
    __shared__ float scr_e[4];
    __shared__ __align__(16) float vcum[16];

    const int tid  = threadIdx.x;
    const int wave = tid >> 6;
    const int lane = tid & 63;
    const int d4   = tid & 3;
    const int ig   = tid >> 2;    // 0..63

    const int bid = blockIdx.x;
    const int b   = bid >> 1;
    const int o0  = (bid & 1) * NITEM;

    const float* base = u_hat + (size_t)b * (N_I * ROWS) + (size_t)o0 * N_D
                      + (size_t)ig * ROWS + (size_t)(d4 << 2);
    float* outb = out + ((size_t)b * N_O + o0) * N_D;

    float4 u[KPT];
    #pragma unroll
    for (int k = 0; k < KPT; ++k)
        u[k] = *(const float4*)(base + (size_t)(k << 6) * ROWS);

    route_item<true >(u, base + 1 * N_D, outb + 0 * N_D, tid, wave, lane, d4,
                      scr_s, scr_e, vcum);
    route_item<true >(u, base + 2 * N_D, outb + 1 * N_D, tid, wave, lane, d4,
                      scr_s, scr_e, vcum);
    route_item<true >(u, base + 3 * N_D, outb + 2 * N_D, tid, wave, lane, d4,
                      scr_s, scr_e, vcum);
    route_item<true >(u, base + 4 * N_D, outb + 3 * N_D, tid, wave, lane, d4,
                      scr_s, scr_e, vcum);
    route_item<false>(u, (const float*)0, outb + 4 * N_D, tid, wave, lane, d4,
                      scr_s, scr_e, vcum);
}

extern "C" void kernel_launch(void* const* d_in, const int* in_sizes, int n_in,
                              void* d_out, int out_size, void* d_ws, size_t ws_size,
                              hipStream_t stream)
{
    const float* u_hat = (const float*)d_in[0];
    float* out = (float*)d_out;
    const int B = in_sizes[0] / (N_I * N_O * N_D);
    hipLaunchKernelGGL(caps_route, dim3(B * 2), dim3(BLK), 0, stream, u_hat, out);
}

// Round 9
// 33.742 us; speedup vs baseline: 1.8941x; 1.8941x over previous
//
#include <hip/hip_runtime.h>
#include <math.h>

#define N_I 1152
#define N_O 10
#define N_D 16
#define BLK 256
#define KPT 18            // i-rows per thread: 1152 / (BLK/4)
#define ROWS (N_O * N_D)  // 160 floats per i-row

// DPP quad_perm butterfly adds (pure VALU, replaces ds_swizzle __shfl_xor):
// xor1 = quad_perm(1,0,3,2) = 0xB1 ; xor2 = quad_perm(2,3,0,1) = 0x4E
__device__ __forceinline__ float qadd1(float x) {
    return x + __int_as_float(__builtin_amdgcn_update_dpp(
        0, __float_as_int(x), 0xB1, 0xF, 0xF, true));
}
__device__ __forceinline__ float qadd2(float x) {
    return x + __int_as_float(__builtin_amdgcn_update_dpp(
        0, __float_as_int(x), 0x4E, 0xF, 0xF, true));
}

// Round-4 one-shot skeleton (allocator-proven: one item, straight-line,
// u[18] in registers, 4 blocks/CU) with the compute window shrunk:
//  - k-loop quad-dot completion via DPP (VALU) instead of ds_swizzle (DS)
//  - epilogue: ALL 256 lanes redundantly combine the 4 wave-partials for
//    their own d4 quad, norm via 2 DPP quad-reduces, vc kept in registers
//    -> 1 barrier per r (ping-pong scratch) instead of 2, no serial tid<16.
__global__ __launch_bounds__(BLK, 4)
void caps_route(const float* __restrict__ u_hat, float* __restrict__ out)
{
    __shared__ float4 scr_s[2][4][4];   // [pingpong][wave][d4]
    __shared__ float  scr_e[2][4];      // [pingpong][wave]

    const int tid  = threadIdx.x;
    const int wave = tid >> 6;
    const int lane = tid & 63;
    const int d4   = tid & 3;
    const int ig   = tid >> 2;    // 0..63

    // XCD-aware swizzle: consecutive wids (same b, adjacent o) on one XCD.
    const int bid = blockIdx.x;
    const int nwg = gridDim.x;
    int wid = bid;
    if ((nwg & 7) == 0) wid = (bid & 7) * (nwg >> 3) + (bid >> 3);
    const int b = wid / N_O;
    const int o = wid - b * N_O;

    const float* g = u_hat + (size_t)b * (N_I * ROWS) + (size_t)o * N_D
                   + (size_t)ig * ROWS + (size_t)(d4 << 2);

    // ---- global -> registers; r=0 partial sums fused under vmcnt ----
    float4 u[KPT];
    float4 s4 = make_float4(0.f, 0.f, 0.f, 0.f);
    #pragma unroll
    for (int k = 0; k < KPT; ++k) {
        u[k] = *(const float4*)(g + (size_t)(k << 6) * ROWS);
        s4.x += u[k].x; s4.y += u[k].y;
        s4.z += u[k].z; s4.w += u[k].w;
    }
    float esum = (float)KPT;     // r=0: b == 0 -> uniform weights, e_i = 1
    float4 vc = make_float4(0.f, 0.f, 0.f, 0.f);
    float4 v4;

    #pragma unroll
    for (int r = 0; r < 3; ++r) {
        if (r > 0) {
            // fused: t_i = u_i . vcum ; e = exp(t_i); s += e*u ; esum += e
            s4 = make_float4(0.f, 0.f, 0.f, 0.f);
            esum = 0.0f;
            #pragma unroll
            for (int k = 0; k < KPT; ++k) {
                float p = u[k].x*vc.x + u[k].y*vc.y + u[k].z*vc.z + u[k].w*vc.w;
                p = qadd1(p);             // DPP quad butterfly: 16-dim dot
                p = qadd2(p);
                const float e = __expf(p);
                esum += e;
                s4.x += e*u[k].x; s4.y += e*u[k].y;
                s4.z += e*u[k].z; s4.w += e*u[k].w;
            }
        }
        // reduce over the 16 ig-groups within the wave (lane bits 2..5)
        #pragma unroll
        for (int m = 4; m <= 32; m <<= 1) {
            s4.x += __shfl_xor(s4.x, m);
            s4.y += __shfl_xor(s4.y, m);
            s4.z += __shfl_xor(s4.z, m);
            s4.w += __shfl_xor(s4.w, m);
            esum += __shfl_xor(esum, m);
        }
        const int pp = r & 1;             // ping-pong: WAR safe w/ 1 barrier
        if (lane < 4) {
            scr_s[pp][wave][lane] = s4;
            if (lane == 0) scr_e[pp][wave] = esum;
        }
        __syncthreads();
        // ALL lanes: combine the 4 wave-partials for their own d4 quad.
        float4 st = make_float4(0.f, 0.f, 0.f, 0.f);
        float et = 0.f;
        #pragma unroll
        for (int w = 0; w < 4; ++w) {
            const float4 t = scr_s[pp][w][d4];
            st.x += t.x; st.y += t.y; st.z += t.z; st.w += t.w;
            et += scr_e[pp][w];
        }
        const float inv = 1.0f / et;      // softmax normalization folded
        st.x *= inv; st.y *= inv; st.z *= inv; st.w *= inv;
        float sq = st.x*st.x + st.y*st.y + st.z*st.z + st.w*st.w;
        sq = qadd1(sq);                   // full ||s||^2 across the 4 quads
        sq = qadd2(sq);
        const float nrm = sqrtf(sq);
        const float f = nrm / (1.0f + sq);   // v = sq*s/((1+sq)*nrm) = s*f
        v4.x = st.x*f; v4.y = st.y*f; v4.z = st.z*f; v4.w = st.w*f;
        if (r < 2) {                      // logit state in REGISTERS
            vc.x += v4.x; vc.y += v4.y; vc.z += v4.z; vc.w += v4.w;
        }
    }
    if (tid < 4)                          // wave0 lanes 0..3 hold d4=0..3
        *(float4*)(out + (size_t)wid * N_D + (tid << 2)) = v4;
}

extern "C" void kernel_launch(void* const* d_in, const int* in_sizes, int n_in,
                              void* d_out, int out_size, void* d_ws, size_t ws_size,
                              hipStream_t stream)
{
    const float* u_hat = (const float*)d_in[0];
    float* out = (float*)d_out;
    const int B = in_sizes[0] / (N_I * N_O * N_D);
    hipLaunchKernelGGL(caps_route, dim3(B * N_O), dim3(BLK), 0, stream, u_hat, out);
}